// Round 9
// baseline (427.588 us; speedup 1.0000x reference)
//
#include <hip/hip_runtime.h>
#include <cmath>

typedef __bf16 bf16x8 __attribute__((ext_vector_type(8)));
typedef float floatx4 __attribute__((ext_vector_type(4)));

typedef __attribute__((address_space(1))) const void* as1_cvp;
typedef __attribute__((address_space(3))) void* as3_vp;

__device__ __forceinline__ void stage16(const void* g, void* l) {
    __builtin_amdgcn_global_load_lds((as1_cvp)g, (as3_vp)l, 16, 0, 0);
}

// ---------------------------------------------------------------------------
// prep_all: segmented launch.
//   [0,6144)        conv inp0 fp32->bf16 -> Ab0
//   [6144,12288)    conv inp1 fp32->bf16 -> Ab1
//   [12288,12504)   pack WT0: 12 kb x 18 cb   (Kd=768)
//   [12504,12936)   pack WT1: 24 kb x 18 cb   (Kd=1536)
//   [12936,13080)   pack WoT: 12 kb x 12 cb
// ---------------------------------------------------------------------------
__global__ void prep_all(
    const float* __restrict__ inp0, const float* __restrict__ inp1,
    const float* __restrict__ Wq0, const float* __restrict__ Wk0, const float* __restrict__ Wv0,
    const float* __restrict__ Wq1, const float* __restrict__ Wk1, const float* __restrict__ Wv1,
    const float* __restrict__ Wo,
    __bf16* __restrict__ Ab0, __bf16* __restrict__ Ab1,
    __bf16* __restrict__ WT0, __bf16* __restrict__ WT1, __bf16* __restrict__ WoT)
{
    __shared__ __bf16 tile[64][72];
    const int bx = blockIdx.x;
    const int tid = threadIdx.x;

    if (bx < 12288) {   // conv segments
        const float* in  = (bx < 6144) ? inp0 : inp1;
        __bf16*      out = (bx < 6144) ? Ab0  : Ab1;
        int t = (bx < 6144 ? bx : bx - 6144) * 256 + tid;
        floatx4 f0 = *(const floatx4*)&in[(size_t)t * 8];
        floatx4 f1 = *(const floatx4*)&in[(size_t)t * 8 + 4];
        bf16x8 o;
#pragma unroll
        for (int j = 0; j < 4; j++) { o[j] = (__bf16)f0[j]; o[4 + j] = (__bf16)f1[j]; }
        *(bf16x8*)&out[(size_t)t * 8] = o;
        return;
    }

    int lane = tid & 63, tr = tid >> 6;

    if (bx < 12936) {   // pack_qkv segments
        int seg1 = (bx >= 12504);
        int idx = seg1 ? bx - 12504 : bx - 12288;
        int nkb = seg1 ? 24 : 12;
        int Kd  = seg1 ? 1536 : 768;
        int off = seg1 ? 384 : 0;
        int k0 = (idx % nkb) * 64, c0 = (idx / nkb) * 64;
        int proj = c0 / 384;
        const float* src = seg1 ? ((proj == 0) ? Wq1 : (proj == 1) ? Wk1 : Wv1)
                                : ((proj == 0) ? Wq0 : (proj == 1) ? Wk0 : Wv0);
        __bf16* WT = seg1 ? WT1 : WT0;
        int col = off + (c0 % 384) + lane;
#pragma unroll
        for (int i = 0; i < 16; i++) {
            int r = i * 4 + tr;
            tile[lane][r] = (__bf16)src[(size_t)(k0 + r) * 768 + col];
        }
        __syncthreads();
#pragma unroll
        for (int i = 0; i < 16; i++) {
            int cl = i * 4 + tr;
            WT[(size_t)(c0 + cl) * Kd + k0 + lane] = tile[cl][lane];
        }
        return;
    }

    {   // pack_wo: WoT[c][k] = Wo[k + (k>=384)*384][c]
        int idx = bx - 12936;
        int k0 = (idx % 12) * 64, c0 = (idx / 12) * 64;
        int col = c0 + lane;
#pragma unroll
        for (int i = 0; i < 16; i++) {
            int k = k0 + i * 4 + tr;
            int srow = k + (k >= 384 ? 384 : 0);
            tile[lane][i * 4 + tr] = (__bf16)Wo[(size_t)srow * 768 + col];
        }
        __syncthreads();
#pragma unroll
        for (int i = 0; i < 16; i++) {
            int cl = i * 4 + tr;
            WoT[(size_t)(c0 + cl) * 768 + k0 + lane] = tile[cl][lane];
        }
        return;
    }
}

// ---------------------------------------------------------------------------
// qkv_all: both levels in one launch. BK=128 (round-4 structure, best
// measured: 108 us). One barrier-pair per 128-K step.
//   grid (LJF): [0,576) L1 blocks (Kd=1536, 12 iters), [576,1728) L0 (6 iters)
// Q gets LOG2E*(q*0.125 + mask) folded in.
// XCD-chunked block swizzle per level; 4-bit LDS involution swizzle.
// proj is block-uniform (col0/384). V blocks (proj==2) route the
// accumulator through the dead As buffer ([128 d][128 n] bf16, chunk-XOR
// swizzled) -> fully coalesced bf16x8 V^T stores.
// ---------------------------------------------------------------------------
__global__ __launch_bounds__(256, 2) void qkv_all(
    const __bf16* __restrict__ Ab0, const __bf16* __restrict__ Ab1,
    const __bf16* __restrict__ WT0, const __bf16* __restrict__ WT1,
    const float* __restrict__ bq0, const float* __restrict__ bk0, const float* __restrict__ bv0,
    const float* __restrict__ bq1, const float* __restrict__ bk1, const float* __restrict__ bv1,
    const float* __restrict__ mask,
    __bf16* __restrict__ Q0, __bf16* __restrict__ K0, __bf16* __restrict__ V0T,
    __bf16* __restrict__ Q1, __bf16* __restrict__ K1, __bf16* __restrict__ V1T)
{
    __shared__ __bf16 As[128 * 128];
    __shared__ __bf16 Bs[128 * 128];
    const int p = blockIdx.x;
    int bx;
    if (p < 576) { bx = 1152 + (p & 7) * 72 + (p >> 3); }        // L1 first (LJF); 72/9=8 panels/XCD
    else { int q = p - 576; bx = (q & 7) * 144 + (q >> 3); }     // L0; 144/9=16 panels/XCD
    const int seg = (bx >= 1152);
    const int idx = seg ? bx - 1152 : bx;
    const int Kd  = seg ? 1536 : 768;
    const int Nl  = seg ? 1024 : 2048;
    const int nlsh = seg ? 10 : 11;
    const int off = seg ? 384 : 0;
    const __bf16* A  = seg ? Ab1 : Ab0;
    const __bf16* BT = seg ? WT1 : WT0;
    const float* bq = seg ? bq1 : bq0;
    const float* bk = seg ? bk1 : bk0;
    const float* bv = seg ? bv1 : bv0;
    __bf16* Qo  = seg ? Q1 : Q0;
    __bf16* Ko  = seg ? K1 : K0;
    __bf16* VTo = seg ? V1T : V0T;

    const int tid = threadIdx.x;
    const int lane = tid & 63;
    const int wave = tid >> 6;
    const int lr = lane & 15, lg = lane >> 4;
    const int col0 = (idx % 9) * 128, row0 = (idx / 9) * 128;
    const int qr = (wave >> 1) * 64, qc = (wave & 1) * 64;
    floatx4 acc[4][4] = {};

    // staging lane decomposition: rl = row-within-4, c16 = 16B chunk 0..15
    const int rl = lane >> 4, c16 = lane & 15;
    // source chunk offsets (elements) for pass j (period 4 in pass index)
    int co[4];
#pragma unroll
    for (int j = 0; j < 4; j++) co[j] = (c16 ^ ((j * 4 + rl) & 15)) * 8;

    const __bf16* ga0 = A  + (size_t)(row0 + wave * 32 + rl) * Kd;
    const __bf16* gb0 = BT + (size_t)(col0 + wave * 32 + rl) * Kd;
    const int nsteps = Kd >> 7;     // 6 (L0) or 12 (L1)

    for (int t = 0; t < nsteps; ++t) {
        const int k0 = t << 7;
#pragma unroll
        for (int i = 0; i < 8; i++) {
            stage16(ga0 + (size_t)(i * 4) * Kd + k0 + co[i & 3], &As[(wave * 32 + i * 4) * 128]);
            stage16(gb0 + (size_t)(i * 4) * Kd + k0 + co[i & 3], &Bs[(wave * 32 + i * 4) * 128]);
        }
        __syncthreads();            // drain stage; tile ready
#pragma unroll
        for (int ch = 0; ch < 4; ch++) {
            bf16x8 af[4], bfr[4];
#pragma unroll
            for (int mt = 0; mt < 4; mt++)
                af[mt] = *(const bf16x8*)&As[(qr + mt * 16 + lr) * 128
                                            + (((ch * 4 + lg) ^ lr) * 8)];
#pragma unroll
            for (int nt = 0; nt < 4; nt++)
                bfr[nt] = *(const bf16x8*)&Bs[(qc + nt * 16 + lr) * 128
                                             + (((ch * 4 + lg) ^ lr) * 8)];
#pragma unroll
            for (int mt = 0; mt < 4; mt++)
#pragma unroll
                for (int nt = 0; nt < 4; nt++)
                    acc[mt][nt] = __builtin_amdgcn_mfma_f32_16x16x32_bf16(af[mt], bfr[nt], acc[mt][nt], 0, 0, 0);
        }
        __syncthreads();            // all reads done before next stage
    }

    const float S_Q = 0.125f * 1.44269504088896f;   // 0.125 * log2(e)
    const float S_M = 1.44269504088896f;            // log2(e)
    const int bproj = col0 / 384;   // block-uniform projection id

    if (bproj == 2) {
        // ---- V path: bias + LDS transpose -> coalesced V^T stores ----
        __bf16* Vt = As;
#pragma unroll
        for (int nt = 0; nt < 4; nt++) {
            int dl = qc + nt * 16 + lr;          // 0..127
            int C = col0 + dl;
            int rem = C - 768;
            float bias = bv[off + rem];
            int dx = (dl & 7) << 3;
#pragma unroll
            for (int mt = 0; mt < 4; mt++) {
#pragma unroll
                for (int r = 0; r < 4; r++) {
                    int nl = qr + mt * 16 + lg * 4 + r;   // 0..127
                    Vt[dl * 128 + (nl ^ dx)] = (__bf16)(acc[mt][nt][r] + bias);
                }
            }
        }
        __syncthreads();
        {
            int dl = tid >> 1;                   // 0..127
            int nh = (tid & 1) << 6;             // 0 or 64
            int C = col0 + dl;
            int rem = C - 768;
            int h = rem >> 6, d = C & 63;
            int b = row0 >> nlsh;
            int nb = row0 & (Nl - 1);
            __bf16* dst = &VTo[((size_t)(b * 6 + h) * 64 + d) * (size_t)Nl + nb + nh];
#pragma unroll
            for (int j = 0; j < 8; j++) {
                int src = dl * 128 + (((nh >> 3) + j) ^ (dl & 7)) * 8;
                *(bf16x8*)&dst[j * 8] = *(const bf16x8*)&Vt[src];
            }
        }
        return;
    }

    // ---- Q/K path (proj 0 or 1, block-uniform) ----
#pragma unroll
    for (int nt = 0; nt < 4; nt++) {
        int C = col0 + qc + nt * 16 + lr;
        int rem = C - bproj * 384;
        int h = rem >> 6, d = C & 63;
        float bias = (bproj == 0) ? bq[off + rem] : bk[off + rem];
#pragma unroll
        for (int mt = 0; mt < 4; mt++) {
#pragma unroll
            for (int r = 0; r < 4; r++) {
                int R = row0 + qr + mt * 16 + lg * 4 + r;
                int b = R >> nlsh;
                int n = R & (Nl - 1);
                size_t hb = (size_t)(b * 6 + h);
                float v = acc[mt][nt][r] + bias;
                if (bproj == 0) {
                    v = fmaf(v, S_Q, S_M * mask[(b << 6) + d]);
                    Qo[(hb * Nl + n) * 64 + d] = (__bf16)v;
                } else {
                    Ko[(hb * Nl + n) * 64 + d] = (__bf16)v;
                }
            }
        }
    }
}

// ---------------------------------------------------------------------------
// attn_all: both levels + pad/mask fill in one launch.  (R4 structure:
// KVBLK=64, 36.9 KB LDS -> 4 blocks/CU.)
//   [0,768)      L0 attn: qb = bx&15, h = (bx>>4)%6, b = bx/96     (Nl=2048)
//   [768,1152)   L1 attn: idx=bx-768; qb=idx&7, h=(idx>>3)%6, b=idx/48 (Nl=1024)
//   [1152,2688)  pad fill of X + output mask
// No-max softmax (Q pre-scaled into exp2 domain), 128 Q rows/block,
// K/V LDS reads shared across 2 Q strips, row-sum l via ones-MFMA.
// NEW: Ps chunk-XOR involution swizzle m(row) = (row&3) ^ (((row>>3)&1)<<1)
// — the scalar bf16 P-pack writes were a 4-way bank conflict (320 cy/round,
// 9.83e6 total) sitting on the serial path before the lgkmcnt fence; with
// the swizzle every wave write instant hits 32 banks x dword-pair (2-way =
// free, m136). Reads (rows lr and 16+lr) share the same m; b128 stays
// 16B-aligned.
// ---------------------------------------------------------------------------
__global__ __launch_bounds__(256, 4) void attn_all(
    const __bf16* __restrict__ Q0, const __bf16* __restrict__ K0, const __bf16* __restrict__ V0T,
    const __bf16* __restrict__ Q1, const __bf16* __restrict__ K1, const __bf16* __restrict__ V1T,
    __bf16* __restrict__ X, float* __restrict__ om)
{
    __shared__ __bf16 Ks[64 * 72];
    __shared__ __bf16 Vs[64 * 72];
    __shared__ __bf16 Ps[4][32 * 72];
    const int p = blockIdx.x;
    int bx;
    if (p < 768) bx = (p & 7) * 96 + (p >> 3);                       // 96/16 = 6 heads/XCD
    else if (p < 1152) { int q = p - 768; bx = 768 + (q & 7) * 48 + (q >> 3); } // 48/8 = 6
    else bx = p;
    const int tid = threadIdx.x;

    if (bx >= 1152) {   // pad + mask segment
        int t = (bx - 1152) * 256 + tid;
        int r = t / 48;
        int c = (t - r * 48) * 8;
        int b = r >> 10, n = 1024 + (r & 1023);
        floatx4 z = {0.f, 0.f, 0.f, 0.f};
        *(floatx4*)&X[(size_t)(b * 2048 + n) * 768 + 384 + c] = z;
        if (t < 4096)
            om[t] = (t < 2048) ? 1.0f : (((t - 2048) < 1024) ? 1.0f : 0.0f);
        return;
    }

    const int seg = (bx >= 768);
    const int idx = seg ? bx - 768 : bx;
    const int Nl = seg ? 1024 : 2048;
    const int qb = seg ? (idx & 7) : (idx & 15);
    const int rest = seg ? (idx >> 3) : (idx >> 4);
    const int h = rest % 6, b = rest / 6;
    const int xoff = seg ? 384 : 0;
    const __bf16* Q  = seg ? Q1 : Q0;
    const __bf16* K  = seg ? K1 : K0;
    const __bf16* VT = seg ? V1T : V0T;

    const int wave = tid >> 6, lane = tid & 63;
    const int lr = lane & 15, lg = lane >> 4;
    const size_t head = (size_t)(b * 6 + h) * Nl * 64;
    const int q0 = qb * 128 + wave * 16;   // strip 0; strip 1 at +64

    // Q strips (2 x 16 rows x 64), A-fragment layout, held in regs all kernel
    bf16x8 qf[2][2];
#pragma unroll
    for (int s = 0; s < 2; s++)
#pragma unroll
        for (int ch = 0; ch < 2; ch++)
            qf[s][ch] = *(const bf16x8*)&Q[head + (size_t)(q0 + s * 64 + lr) * 64 + ch * 32 + lg * 8];

    // constant ones B-fragment for the row-sum MFMA
    bf16x8 onesv;
#pragma unroll
    for (int j = 0; j < 8; j++) onesv[j] = (__bf16)1.0f;

    const int rr = tid >> 2, cc = (tid & 3) * 16;
    const __bf16* Kg = K + head;
    const __bf16* Vg = VT + head;

    // Ps swizzle masks: write side m = r ^ ((lg>>1)<<1); read side (row=lr
    // or 16+lr) m = (lr&3) ^ (((lr>>3)&1)<<1).
    const int mread = (lr & 3) ^ (((lr >> 3) & 1) << 1);

    // prefetch tile 0 into registers
    bf16x8 kr0, kr1, vr0, vr1;
    {
        size_t kb = (size_t)rr * 64 + cc;
        kr0 = *(const bf16x8*)&Kg[kb];
        kr1 = *(const bf16x8*)&Kg[kb + 8];
        size_t vb = (size_t)rr * Nl + cc;
        vr0 = *(const bf16x8*)&Vg[vb];
        vr1 = *(const bf16x8*)&Vg[vb + 8];
    }

    floatx4 o_acc[2][4] = {};
    floatx4 l_acc[2] = {};

    for (int n0 = 0; n0 < Nl; n0 += 64) {
        __syncthreads();                       // prior tile's LDS reads done
        *(bf16x8*)&Ks[rr * 72 + cc]     = kr0;
        *(bf16x8*)&Ks[rr * 72 + cc + 8] = kr1;
        *(bf16x8*)&Vs[rr * 72 + cc]     = vr0;
        *(bf16x8*)&Vs[rr * 72 + cc + 8] = vr1;
        __syncthreads();                       // LDS tile ready

        // prefetch next tile (drains at next barrier; overlaps compute)
        if (n0 + 64 < Nl) {
            size_t kb = (size_t)(n0 + 64 + rr) * 64 + cc;
            kr0 = *(const bf16x8*)&Kg[kb];
            kr1 = *(const bf16x8*)&Kg[kb + 8];
            size_t vb = (size_t)rr * Nl + n0 + 64 + cc;
            vr0 = *(const bf16x8*)&Vg[vb];
            vr1 = *(const bf16x8*)&Vg[vb + 8];
        }

        // S = Q K^T  (already in exp2 domain); K read shared across strips
        floatx4 sv[2][4] = {};
        __builtin_amdgcn_s_setprio(1);
#pragma unroll
        for (int ch = 0; ch < 2; ch++) {
#pragma unroll
            for (int nt = 0; nt < 4; nt++) {
                bf16x8 kb8 = *(const bf16x8*)&Ks[(nt * 16 + lr) * 72 + ch * 32 + lg * 8];
                sv[0][nt] = __builtin_amdgcn_mfma_f32_16x16x32_bf16(qf[0][ch], kb8, sv[0][nt], 0, 0, 0);
                sv[1][nt] = __builtin_amdgcn_mfma_f32_16x16x32_bf16(qf[1][ch], kb8, sv[1][nt], 0, 0, 0);
            }
        }
        __builtin_amdgcn_s_setprio(0);

        // P = exp2(S), packed to bf16 in per-wave LDS (C-layout -> A-layout)
        // chunk-XOR swizzled: phys chunk = (nt*2 + (lr>>3)) ^ r ^ ((lg>>1)<<1)
#pragma unroll
        for (int s = 0; s < 2; s++)
#pragma unroll
            for (int nt = 0; nt < 4; nt++)
#pragma unroll
                for (int r = 0; r < 4; r++) {
                    float p2 = __builtin_amdgcn_exp2f(sv[s][nt][r]);
                    int row = s * 16 + lg * 4 + r;
                    int chP = (nt * 2 + (lr >> 3)) ^ r ^ (((lg >> 1) & 1) << 1);
                    Ps[wave][row * 72 + chP * 8 + (lr & 7)] = (__bf16)p2;
                }
        // per-wave DS is in-order on HW; asm blocks compiler reordering
        asm volatile("s_waitcnt lgkmcnt(0)" ::: "memory");

        // O += P V ; l += P * ones  (V read shared across strips)
        __builtin_amdgcn_s_setprio(1);
#pragma unroll
        for (int ch = 0; ch < 2; ch++) {
            bf16x8 pa0 = *(const bf16x8*)&Ps[wave][lr * 72 + (((ch * 4 + lg) ^ mread) * 8)];
            bf16x8 pa1 = *(const bf16x8*)&Ps[wave][(16 + lr) * 72 + (((ch * 4 + lg) ^ mread) * 8)];
#pragma unroll
            for (int dt = 0; dt < 4; dt++) {
                bf16x8 vb8 = *(const bf16x8*)&Vs[(dt * 16 + lr) * 72 + ch * 32 + lg * 8];
                o_acc[0][dt] = __builtin_amdgcn_mfma_f32_16x16x32_bf16(pa0, vb8, o_acc[0][dt], 0, 0, 0);
                o_acc[1][dt] = __builtin_amdgcn_mfma_f32_16x16x32_bf16(pa1, vb8, o_acc[1][dt], 0, 0, 0);
            }
            l_acc[0] = __builtin_amdgcn_mfma_f32_16x16x32_bf16(pa0, onesv, l_acc[0], 0, 0, 0);
            l_acc[1] = __builtin_amdgcn_mfma_f32_16x16x32_bf16(pa1, onesv, l_acc[1], 0, 0, 0);
        }
        __builtin_amdgcn_s_setprio(0);
    }

#pragma unroll
    for (int s = 0; s < 2; s++)
#pragma unroll
        for (int dt = 0; dt < 4; dt++)
#pragma unroll
            for (int r = 0; r < 4; r++) {
                int n = q0 + s * 64 + lg * 4 + r;
                float o = o_acc[s][dt][r] / l_acc[s][r];
                X[(size_t)(b * 2048 + n) * 768 + xoff + h * 64 + dt * 16 + lr] = (__bf16)o;
            }
}

// ---------------------------------------------------------------------------
// Output GEMM: X(bf16)[16384][768] @ WoT[768][768]^T + bo -> out fp32.
// Grid: 768 blocks = 6 col-blocks x 128 row-blocks, XCD-chunked swizzle.
// BK=128 (6 iters), 4-bit involution swizzle, one barrier-pair per step.
// (round-4 structure, best measured)
// ---------------------------------------------------------------------------
__global__ __launch_bounds__(256, 2) void out_gemm(
    const __bf16* __restrict__ A, const __bf16* __restrict__ BT,
    const float* __restrict__ bo, float* __restrict__ out)
{
    __shared__ __bf16 As[128 * 128];
    __shared__ __bf16 Bs[128 * 128];
    const int tid = threadIdx.x;
    const int lane = tid & 63;
    const int wave = tid >> 6;
    const int lr = lane & 15, lg = lane >> 4;
    const int p = blockIdx.x;
    const int bx = (p & 7) * 96 + (p >> 3);     // 96/6 = 16 panels/XCD
    const int col0 = (bx % 6) * 128, row0 = (bx / 6) * 128;
    const int qr = (wave >> 1) * 64, qc = (wave & 1) * 64;
    const int Kd = 768;
    floatx4 acc[4][4] = {};

    const int rl = lane >> 4, c16 = lane & 15;
    int co[4];
#pragma unroll
    for (int j = 0; j < 4; j++) co[j] = (c16 ^ ((j * 4 + rl) & 15)) * 8;

    const __bf16* ga0 = A  + (size_t)(row0 + wave * 32 + rl) * Kd;
    const __bf16* gb0 = BT + (size_t)(col0 + wave * 32 + rl) * Kd;
    const int nsteps = Kd >> 7;   // 6

    for (int t = 0; t < nsteps; ++t) {
        const int k0 = t << 7;
#pragma unroll
        for (int i = 0; i < 8; i++) {
            stage16(ga0 + (size_t)(i * 4) * Kd + k0 + co[i & 3], &As[(wave * 32 + i * 4) * 128]);
            stage16(gb0 + (size_t)(i * 4) * Kd + k0 + co[i & 3], &Bs[(wave * 32 + i * 4) * 128]);
        }
        __syncthreads();
#pragma unroll
        for (int ch = 0; ch < 4; ch++) {
            bf16x8 af[4], bfr[4];
#pragma unroll
            for (int mt = 0; mt < 4; mt++)
                af[mt] = *(const bf16x8*)&As[(qr + mt * 16 + lr) * 128
                                            + (((ch * 4 + lg) ^ lr) * 8)];
#pragma unroll
            for (int nt = 0; nt < 4; nt++)
                bfr[nt] = *(const bf16x8*)&Bs[(qc + nt * 16 + lr) * 128
                                             + (((ch * 4 + lg) ^ lr) * 8)];
#pragma unroll
            for (int mt = 0; mt < 4; mt++)
#pragma unroll
                for (int nt = 0; nt < 4; nt++)
                    acc[mt][nt] = __builtin_amdgcn_mfma_f32_16x16x32_bf16(af[mt], bfr[nt], acc[mt][nt], 0, 0, 0);
        }
        __syncthreads();
    }

#pragma unroll
    for (int nt = 0; nt < 4; nt++) {
        int C = col0 + qc + nt * 16 + lr;
        float bias = bo[C];
#pragma unroll
        for (int mt = 0; mt < 4; mt++) {
#pragma unroll
            for (int r = 0; r < 4; r++) {
                int R = row0 + qr + mt * 16 + lg * 4 + r;
                out[(size_t)R * 768 + C] = acc[mt][nt][r] + bias;
            }
        }
    }
}

// ---------------------------------------------------------------------------
extern "C" void kernel_launch(void* const* d_in, const int* in_sizes, int n_in,
                              void* d_out, int out_size, void* d_ws, size_t ws_size,
                              hipStream_t stream)
{
    // All reference inputs are float32; output is float32.
    const float* inp0  = (const float*)d_in[0];
    const float* inp1  = (const float*)d_in[1];
    const float* amask = (const float*)d_in[2];
    const float* Wq0 = (const float*)d_in[3];
    const float* bq0 = (const float*)d_in[4];
    const float* Wk0 = (const float*)d_in[5];
    const float* bk0 = (const float*)d_in[6];
    const float* Wv0 = (const float*)d_in[7];
    const float* bv0 = (const float*)d_in[8];
    const float* Wq1 = (const float*)d_in[9];
    const float* bq1 = (const float*)d_in[10];
    const float* Wk1 = (const float*)d_in[11];
    const float* bk1 = (const float*)d_in[12];
    const float* Wv1 = (const float*)d_in[13];
    const float* bv1 = (const float*)d_in[14];
    const float* Wo  = (const float*)d_in[15];
    const float* bo  = (const float*)d_in[16];

    // Workspace layout (bytes), peak ~126.0 MB.
    // X aliases Ab0 (Ab0 is dead after qkv_all; stream order protects it).
    char* ws = (char*)d_ws;
    __bf16* WT0 = (__bf16*)(ws + 0);            // 1152x768  bf16 (1,769,472)
    __bf16* WT1 = (__bf16*)(ws + 1769472);      // 1152x1536 bf16 (3,538,944)
    __bf16* WoT = (__bf16*)(ws + 5308416);      // 768x768   bf16 (1,179,648)
    __bf16* Ab0 = (__bf16*)(ws + 6488064);      // 12.58M bf16 (25,165,824)
    __bf16* X   = Ab0;                          // alias
    __bf16* Ab1 = (__bf16*)(ws + 31653888);     // 12.58M bf16 (25,165,824)
    __bf16* Q0  = (__bf16*)(ws + 56819712);     // 8*6*2048*64 bf16 (12,582,912)
    __bf16* K0  = (__bf16*)(ws + 69402624);
    __bf16* V0T = (__bf16*)(ws + 81985536);
    __bf16* Q1  = (__bf16*)(ws + 94568448);     // 8*6*1024*64 bf16 (6,291,456)
    __bf16* K1  = (__bf16*)(ws + 100859904);
    __bf16* V1T = (__bf16*)(ws + 107151360);    // ends 113,442,816
    float* outp = (float*)d_out;

    hipLaunchKernelGGL(prep_all, dim3(13080), dim3(256), 0, stream,
                       inp0, inp1, Wq0, Wk0, Wv0, Wq1, Wk1, Wv1, Wo,
                       Ab0, Ab1, WT0, WT1, WoT);
    hipLaunchKernelGGL(qkv_all, dim3(1728), dim3(256), 0, stream,
                       Ab0, Ab1, WT0, WT1,
                       bq0, bk0, bv0, bq1, bk1, bv1, amask,
                       Q0, K0, V0T, Q1, K1, V1T);
    hipLaunchKernelGGL(attn_all, dim3(2688), dim3(256), 0, stream,
                       Q0, K0, V0T, Q1, K1, V1T, X, outp + 12582912);
    hipLaunchKernelGGL(out_gemm, dim3(768), dim3(256), 0, stream,
                       X, WoT, bo, outp);
}

// Round 10
// 387.588 us; speedup vs baseline: 1.1032x; 1.1032x over previous
//
#include <hip/hip_runtime.h>
#include <cmath>

typedef __bf16 bf16x8 __attribute__((ext_vector_type(8)));
typedef float floatx4 __attribute__((ext_vector_type(4)));

typedef __attribute__((address_space(1))) const void* as1_cvp;
typedef __attribute__((address_space(3))) void* as3_vp;

__device__ __forceinline__ void stage16(const void* g, void* l) {
    __builtin_amdgcn_global_load_lds((as1_cvp)g, (as3_vp)l, 16, 0, 0);
}

// ---------------------------------------------------------------------------
// prep_all: segmented launch.
//   [0,6144)        conv inp0 fp32->bf16 -> Ab0
//   [6144,12288)    conv inp1 fp32->bf16 -> Ab1
//   [12288,12504)   pack WT0: 12 kb x 18 cb   (Kd=768)
//   [12504,12936)   pack WT1: 24 kb x 18 cb   (Kd=1536)
//   [12936,13080)   pack WoT: 12 kb x 12 cb
// ---------------------------------------------------------------------------
__global__ void prep_all(
    const float* __restrict__ inp0, const float* __restrict__ inp1,
    const float* __restrict__ Wq0, const float* __restrict__ Wk0, const float* __restrict__ Wv0,
    const float* __restrict__ Wq1, const float* __restrict__ Wk1, const float* __restrict__ Wv1,
    const float* __restrict__ Wo,
    __bf16* __restrict__ Ab0, __bf16* __restrict__ Ab1,
    __bf16* __restrict__ WT0, __bf16* __restrict__ WT1, __bf16* __restrict__ WoT)
{
    __shared__ __bf16 tile[64][72];
    const int bx = blockIdx.x;
    const int tid = threadIdx.x;

    if (bx < 12288) {   // conv segments
        const float* in  = (bx < 6144) ? inp0 : inp1;
        __bf16*      out = (bx < 6144) ? Ab0  : Ab1;
        int t = (bx < 6144 ? bx : bx - 6144) * 256 + tid;
        floatx4 f0 = *(const floatx4*)&in[(size_t)t * 8];
        floatx4 f1 = *(const floatx4*)&in[(size_t)t * 8 + 4];
        bf16x8 o;
#pragma unroll
        for (int j = 0; j < 4; j++) { o[j] = (__bf16)f0[j]; o[4 + j] = (__bf16)f1[j]; }
        *(bf16x8*)&out[(size_t)t * 8] = o;
        return;
    }

    int lane = tid & 63, tr = tid >> 6;

    if (bx < 12936) {   // pack_qkv segments
        int seg1 = (bx >= 12504);
        int idx = seg1 ? bx - 12504 : bx - 12288;
        int nkb = seg1 ? 24 : 12;
        int Kd  = seg1 ? 1536 : 768;
        int off = seg1 ? 384 : 0;
        int k0 = (idx % nkb) * 64, c0 = (idx / nkb) * 64;
        int proj = c0 / 384;
        const float* src = seg1 ? ((proj == 0) ? Wq1 : (proj == 1) ? Wk1 : Wv1)
                                : ((proj == 0) ? Wq0 : (proj == 1) ? Wk0 : Wv0);
        __bf16* WT = seg1 ? WT1 : WT0;
        int col = off + (c0 % 384) + lane;
#pragma unroll
        for (int i = 0; i < 16; i++) {
            int r = i * 4 + tr;
            tile[lane][r] = (__bf16)src[(size_t)(k0 + r) * 768 + col];
        }
        __syncthreads();
#pragma unroll
        for (int i = 0; i < 16; i++) {
            int cl = i * 4 + tr;
            WT[(size_t)(c0 + cl) * Kd + k0 + lane] = tile[cl][lane];
        }
        return;
    }

    {   // pack_wo: WoT[c][k] = Wo[k + (k>=384)*384][c]
        int idx = bx - 12936;
        int k0 = (idx % 12) * 64, c0 = (idx / 12) * 64;
        int col = c0 + lane;
#pragma unroll
        for (int i = 0; i < 16; i++) {
            int k = k0 + i * 4 + tr;
            int srow = k + (k >= 384 ? 384 : 0);
            tile[lane][i * 4 + tr] = (__bf16)Wo[(size_t)srow * 768 + col];
        }
        __syncthreads();
#pragma unroll
        for (int i = 0; i < 16; i++) {
            int cl = i * 4 + tr;
            WoT[(size_t)(c0 + cl) * 768 + k0 + lane] = tile[cl][lane];
        }
        return;
    }
}

// ---------------------------------------------------------------------------
// qkv_all: both levels in one launch. BK=128 (round-4 structure).
//   grid (LJF): [0,576) L1 blocks (Kd=1536, 12 iters), [576,1728) L0 (6 iters)
// Q gets LOG2E*(q*0.125 + mask) folded in.
// XCD-chunked block swizzle per level; 4-bit LDS involution swizzle.
// proj is block-uniform (col0/384). V blocks (proj==2) route the
// accumulator through the dead As buffer -> coalesced bf16x8 V^T stores.
// (R8 version, verbatim — best measured.)
// ---------------------------------------------------------------------------
__global__ __launch_bounds__(256, 2) void qkv_all(
    const __bf16* __restrict__ Ab0, const __bf16* __restrict__ Ab1,
    const __bf16* __restrict__ WT0, const __bf16* __restrict__ WT1,
    const float* __restrict__ bq0, const float* __restrict__ bk0, const float* __restrict__ bv0,
    const float* __restrict__ bq1, const float* __restrict__ bk1, const float* __restrict__ bv1,
    const float* __restrict__ mask,
    __bf16* __restrict__ Q0, __bf16* __restrict__ K0, __bf16* __restrict__ V0T,
    __bf16* __restrict__ Q1, __bf16* __restrict__ K1, __bf16* __restrict__ V1T)
{
    __shared__ __bf16 As[128 * 128];
    __shared__ __bf16 Bs[128 * 128];
    const int p = blockIdx.x;
    int bx;
    if (p < 576) { bx = 1152 + (p & 7) * 72 + (p >> 3); }        // L1 first (LJF); 72/9=8 panels/XCD
    else { int q = p - 576; bx = (q & 7) * 144 + (q >> 3); }     // L0; 144/9=16 panels/XCD
    const int seg = (bx >= 1152);
    const int idx = seg ? bx - 1152 : bx;
    const int Kd  = seg ? 1536 : 768;
    const int Nl  = seg ? 1024 : 2048;
    const int nlsh = seg ? 10 : 11;
    const int off = seg ? 384 : 0;
    const __bf16* A  = seg ? Ab1 : Ab0;
    const __bf16* BT = seg ? WT1 : WT0;
    const float* bq = seg ? bq1 : bq0;
    const float* bk = seg ? bk1 : bk0;
    const float* bv = seg ? bv1 : bv0;
    __bf16* Qo  = seg ? Q1 : Q0;
    __bf16* Ko  = seg ? K1 : K0;
    __bf16* VTo = seg ? V1T : V0T;

    const int tid = threadIdx.x;
    const int lane = tid & 63;
    const int wave = tid >> 6;
    const int lr = lane & 15, lg = lane >> 4;
    const int col0 = (idx % 9) * 128, row0 = (idx / 9) * 128;
    const int qr = (wave >> 1) * 64, qc = (wave & 1) * 64;
    floatx4 acc[4][4] = {};

    // staging lane decomposition: rl = row-within-4, c16 = 16B chunk 0..15
    const int rl = lane >> 4, c16 = lane & 15;
    int co[4];
#pragma unroll
    for (int j = 0; j < 4; j++) co[j] = (c16 ^ ((j * 4 + rl) & 15)) * 8;

    const __bf16* ga0 = A  + (size_t)(row0 + wave * 32 + rl) * Kd;
    const __bf16* gb0 = BT + (size_t)(col0 + wave * 32 + rl) * Kd;
    const int nsteps = Kd >> 7;     // 6 (L0) or 12 (L1)

    for (int t = 0; t < nsteps; ++t) {
        const int k0 = t << 7;
#pragma unroll
        for (int i = 0; i < 8; i++) {
            stage16(ga0 + (size_t)(i * 4) * Kd + k0 + co[i & 3], &As[(wave * 32 + i * 4) * 128]);
            stage16(gb0 + (size_t)(i * 4) * Kd + k0 + co[i & 3], &Bs[(wave * 32 + i * 4) * 128]);
        }
        __syncthreads();            // drain stage; tile ready
#pragma unroll
        for (int ch = 0; ch < 4; ch++) {
            bf16x8 af[4], bfr[4];
#pragma unroll
            for (int mt = 0; mt < 4; mt++)
                af[mt] = *(const bf16x8*)&As[(qr + mt * 16 + lr) * 128
                                            + (((ch * 4 + lg) ^ lr) * 8)];
#pragma unroll
            for (int nt = 0; nt < 4; nt++)
                bfr[nt] = *(const bf16x8*)&Bs[(qc + nt * 16 + lr) * 128
                                             + (((ch * 4 + lg) ^ lr) * 8)];
#pragma unroll
            for (int mt = 0; mt < 4; mt++)
#pragma unroll
                for (int nt = 0; nt < 4; nt++)
                    acc[mt][nt] = __builtin_amdgcn_mfma_f32_16x16x32_bf16(af[mt], bfr[nt], acc[mt][nt], 0, 0, 0);
        }
        __syncthreads();            // all reads done before next stage
    }

    const float S_Q = 0.125f * 1.44269504088896f;   // 0.125 * log2(e)
    const float S_M = 1.44269504088896f;            // log2(e)
    const int bproj = col0 / 384;   // block-uniform projection id

    if (bproj == 2) {
        // ---- V path: bias + LDS transpose -> coalesced V^T stores ----
        __bf16* Vt = As;
#pragma unroll
        for (int nt = 0; nt < 4; nt++) {
            int dl = qc + nt * 16 + lr;          // 0..127
            int C = col0 + dl;
            int rem = C - 768;
            float bias = bv[off + rem];
            int dx = (dl & 7) << 3;
#pragma unroll
            for (int mt = 0; mt < 4; mt++) {
#pragma unroll
                for (int r = 0; r < 4; r++) {
                    int nl = qr + mt * 16 + lg * 4 + r;   // 0..127
                    Vt[dl * 128 + (nl ^ dx)] = (__bf16)(acc[mt][nt][r] + bias);
                }
            }
        }
        __syncthreads();
        {
            int dl = tid >> 1;                   // 0..127
            int nh = (tid & 1) << 6;             // 0 or 64
            int C = col0 + dl;
            int rem = C - 768;
            int h = rem >> 6, d = C & 63;
            int b = row0 >> nlsh;
            int nb = row0 & (Nl - 1);
            __bf16* dst = &VTo[((size_t)(b * 6 + h) * 64 + d) * (size_t)Nl + nb + nh];
#pragma unroll
            for (int j = 0; j < 8; j++) {
                int src = dl * 128 + (((nh >> 3) + j) ^ (dl & 7)) * 8;
                *(bf16x8*)&dst[j * 8] = *(const bf16x8*)&Vt[src];
            }
        }
        return;
    }

    // ---- Q/K path (proj 0 or 1, block-uniform) ----
#pragma unroll
    for (int nt = 0; nt < 4; nt++) {
        int C = col0 + qc + nt * 16 + lr;
        int rem = C - bproj * 384;
        int h = rem >> 6, d = C & 63;
        float bias = (bproj == 0) ? bq[off + rem] : bk[off + rem];
#pragma unroll
        for (int mt = 0; mt < 4; mt++) {
#pragma unroll
            for (int r = 0; r < 4; r++) {
                int R = row0 + qr + mt * 16 + lg * 4 + r;
                int b = R >> nlsh;
                int n = R & (Nl - 1);
                size_t hb = (size_t)(b * 6 + h);
                float v = acc[mt][nt][r] + bias;
                if (bproj == 0) {
                    v = fmaf(v, S_Q, S_M * mask[(b << 6) + d]);
                    Qo[(hb * Nl + n) * 64 + d] = (__bf16)v;
                } else {
                    Ko[(hb * Nl + n) * 64 + d] = (__bf16)v;
                }
            }
        }
    }
}

// ---------------------------------------------------------------------------
// attn_all: both levels + pad/mask fill in one launch.
// NEW GEOMETRY: 512 threads (8 waves), QBLK=256 (each wave owns 2 strips of
// 16 rows: q0 and q0+128). K/V tile (64-wide) shared by 8 waves -> per-wave
// staging halves; barrier rounds 30720 -> 15360 at CONSTANT 16 waves/CU
// (LDS 55.3 KB -> 2 blocks x 8 waves; previous 36.9 KB -> 4 blocks x 4).
// This is the R4 lever (rounds halved, occupancy held) — R6's mistake
// (occupancy halved) is avoided. Per-wave inner structure identical to R8;
// Ps layout is the R8 original (R9 swizzle reverted: codegen pathology).
//   [0,384)    L0 attn: qb = bx&7,  rest = bx>>3  (Nl=2048, 32 rounds)
//   [384,576)  L1 attn: qb = idx&3, rest = idx>>2 (Nl=1024, 16 rounds)
//   [576,1344) pad fill of X + output mask (512 threads each)
// ---------------------------------------------------------------------------
__global__ __launch_bounds__(512, 4) void attn_all(
    const __bf16* __restrict__ Q0, const __bf16* __restrict__ K0, const __bf16* __restrict__ V0T,
    const __bf16* __restrict__ Q1, const __bf16* __restrict__ K1, const __bf16* __restrict__ V1T,
    __bf16* __restrict__ X, float* __restrict__ om)
{
    __shared__ __bf16 Ks[64 * 72];
    __shared__ __bf16 Vs[64 * 72];
    __shared__ __bf16 Ps[8][32 * 72];
    const int p = blockIdx.x;
    int bx;
    if (p < 384) bx = (p & 7) * 48 + (p >> 3);                       // 48/8 = 6 heads/XCD
    else if (p < 576) { int q = p - 384; bx = 384 + (q & 7) * 24 + (q >> 3); } // 24/4 = 6
    else bx = p;
    const int tid = threadIdx.x;

    if (bx >= 576) {   // pad + mask segment
        int t = (bx - 576) * 512 + tid;
        int r = t / 48;
        int c = (t - r * 48) * 8;
        int b = r >> 10, n = 1024 + (r & 1023);
        floatx4 z = {0.f, 0.f, 0.f, 0.f};
        *(floatx4*)&X[(size_t)(b * 2048 + n) * 768 + 384 + c] = z;
        if (t < 4096)
            om[t] = (t < 2048) ? 1.0f : (((t - 2048) < 1024) ? 1.0f : 0.0f);
        return;
    }

    const int seg = (bx >= 384);
    const int idx = seg ? bx - 384 : bx;
    const int Nl = seg ? 1024 : 2048;
    const int qb = seg ? (idx & 3) : (idx & 7);
    const int rest = seg ? (idx >> 2) : (idx >> 3);
    const int h = rest % 6, b = rest / 6;
    const int xoff = seg ? 384 : 0;
    const __bf16* Q  = seg ? Q1 : Q0;
    const __bf16* K  = seg ? K1 : K0;
    const __bf16* VT = seg ? V1T : V0T;

    const int wave = tid >> 6, lane = tid & 63;
    const int lr = lane & 15, lg = lane >> 4;
    const size_t head = (size_t)(b * 6 + h) * Nl * 64;
    const int q0 = qb * 256 + wave * 16;   // strip 0; strip 1 at +128

    // Q strips (2 x 16 rows x 64), A-fragment layout, held in regs all kernel
    bf16x8 qf[2][2];
#pragma unroll
    for (int s = 0; s < 2; s++)
#pragma unroll
        for (int ch = 0; ch < 2; ch++)
            qf[s][ch] = *(const bf16x8*)&Q[head + (size_t)(q0 + s * 128 + lr) * 64 + ch * 32 + lg * 8];

    // constant ones B-fragment for the row-sum MFMA
    bf16x8 onesv;
#pragma unroll
    for (int j = 0; j < 8; j++) onesv[j] = (__bf16)1.0f;

    // staging map: 512 threads x 16B = one 8KB tile each for K and V
    const int rr = tid >> 3, cc = (tid & 7) * 8;
    const __bf16* Kg = K + head;
    const __bf16* Vg = VT + head;

    // prefetch tile 0 into registers (one bf16x8 each)
    bf16x8 kr0 = *(const bf16x8*)&Kg[(size_t)rr * 64 + cc];
    bf16x8 vr0 = *(const bf16x8*)&Vg[(size_t)rr * Nl + cc];

    floatx4 o_acc[2][4] = {};
    floatx4 l_acc[2] = {};

    for (int n0 = 0; n0 < Nl; n0 += 64) {
        __syncthreads();                       // prior tile's LDS reads done
        *(bf16x8*)&Ks[rr * 72 + cc] = kr0;
        *(bf16x8*)&Vs[rr * 72 + cc] = vr0;
        __syncthreads();                       // LDS tile ready

        // prefetch next tile (overlaps compute)
        if (n0 + 64 < Nl) {
            kr0 = *(const bf16x8*)&Kg[(size_t)(n0 + 64 + rr) * 64 + cc];
            vr0 = *(const bf16x8*)&Vg[(size_t)rr * Nl + n0 + 64 + cc];
        }

        // S = Q K^T  (already in exp2 domain); K read shared across strips
        floatx4 sv[2][4] = {};
        __builtin_amdgcn_s_setprio(1);
#pragma unroll
        for (int ch = 0; ch < 2; ch++) {
#pragma unroll
            for (int nt = 0; nt < 4; nt++) {
                bf16x8 kb8 = *(const bf16x8*)&Ks[(nt * 16 + lr) * 72 + ch * 32 + lg * 8];
                sv[0][nt] = __builtin_amdgcn_mfma_f32_16x16x32_bf16(qf[0][ch], kb8, sv[0][nt], 0, 0, 0);
                sv[1][nt] = __builtin_amdgcn_mfma_f32_16x16x32_bf16(qf[1][ch], kb8, sv[1][nt], 0, 0, 0);
            }
        }
        __builtin_amdgcn_s_setprio(0);

        // P = exp2(S), packed to bf16 in per-wave LDS (C-layout -> A-layout)
#pragma unroll
        for (int s = 0; s < 2; s++)
#pragma unroll
            for (int nt = 0; nt < 4; nt++)
#pragma unroll
                for (int r = 0; r < 4; r++) {
                    float p2 = __builtin_amdgcn_exp2f(sv[s][nt][r]);
                    Ps[wave][(s * 16 + lg * 4 + r) * 72 + nt * 16 + lr] = (__bf16)p2;
                }
        // per-wave DS is in-order on HW; asm blocks compiler reordering
        asm volatile("s_waitcnt lgkmcnt(0)" ::: "memory");

        // O += P V ; l += P * ones  (V read shared across strips)
        __builtin_amdgcn_s_setprio(1);
#pragma unroll
        for (int ch = 0; ch < 2; ch++) {
            bf16x8 pa0 = *(const bf16x8*)&Ps[wave][lr * 72 + ch * 32 + lg * 8];
            bf16x8 pa1 = *(const bf16x8*)&Ps[wave][(16 + lr) * 72 + ch * 32 + lg * 8];
#pragma unroll
            for (int dt = 0; dt < 4; dt++) {
                bf16x8 vb8 = *(const bf16x8*)&Vs[(dt * 16 + lr) * 72 + ch * 32 + lg * 8];
                o_acc[0][dt] = __builtin_amdgcn_mfma_f32_16x16x32_bf16(pa0, vb8, o_acc[0][dt], 0, 0, 0);
                o_acc[1][dt] = __builtin_amdgcn_mfma_f32_16x16x32_bf16(pa1, vb8, o_acc[1][dt], 0, 0, 0);
            }
            l_acc[0] = __builtin_amdgcn_mfma_f32_16x16x32_bf16(pa0, onesv, l_acc[0], 0, 0, 0);
            l_acc[1] = __builtin_amdgcn_mfma_f32_16x16x32_bf16(pa1, onesv, l_acc[1], 0, 0, 0);
        }
        __builtin_amdgcn_s_setprio(0);
    }

#pragma unroll
    for (int s = 0; s < 2; s++)
#pragma unroll
        for (int dt = 0; dt < 4; dt++)
#pragma unroll
            for (int r = 0; r < 4; r++) {
                int n = q0 + s * 128 + lg * 4 + r;
                float o = o_acc[s][dt][r] / l_acc[s][r];
                X[(size_t)(b * 2048 + n) * 768 + xoff + h * 64 + dt * 16 + lr] = (__bf16)o;
            }
}

// ---------------------------------------------------------------------------
// Output GEMM: X(bf16)[16384][768] @ WoT[768][768]^T + bo -> out fp32.
// Grid: 768 blocks = 6 col-blocks x 128 row-blocks, XCD-chunked swizzle.
// BK=128 (6 iters), 4-bit involution swizzle, one barrier-pair per step.
// (R8 verbatim.)
// ---------------------------------------------------------------------------
__global__ __launch_bounds__(256, 2) void out_gemm(
    const __bf16* __restrict__ A, const __bf16* __restrict__ BT,
    const float* __restrict__ bo, float* __restrict__ out)
{
    __shared__ __bf16 As[128 * 128];
    __shared__ __bf16 Bs[128 * 128];
    const int tid = threadIdx.x;
    const int lane = tid & 63;
    const int wave = tid >> 6;
    const int lr = lane & 15, lg = lane >> 4;
    const int p = blockIdx.x;
    const int bx = (p & 7) * 96 + (p >> 3);     // 96/6 = 16 panels/XCD
    const int col0 = (bx % 6) * 128, row0 = (bx / 6) * 128;
    const int qr = (wave >> 1) * 64, qc = (wave & 1) * 64;
    const int Kd = 768;
    floatx4 acc[4][4] = {};

    const int rl = lane >> 4, c16 = lane & 15;
    int co[4];
#pragma unroll
    for (int j = 0; j < 4; j++) co[j] = (c16 ^ ((j * 4 + rl) & 15)) * 8;

    const __bf16* ga0 = A  + (size_t)(row0 + wave * 32 + rl) * Kd;
    const __bf16* gb0 = BT + (size_t)(col0 + wave * 32 + rl) * Kd;
    const int nsteps = Kd >> 7;   // 6

    for (int t = 0; t < nsteps; ++t) {
        const int k0 = t << 7;
#pragma unroll
        for (int i = 0; i < 8; i++) {
            stage16(ga0 + (size_t)(i * 4) * Kd + k0 + co[i & 3], &As[(wave * 32 + i * 4) * 128]);
            stage16(gb0 + (size_t)(i * 4) * Kd + k0 + co[i & 3], &Bs[(wave * 32 + i * 4) * 128]);
        }
        __syncthreads();
#pragma unroll
        for (int ch = 0; ch < 4; ch++) {
            bf16x8 af[4], bfr[4];
#pragma unroll
            for (int mt = 0; mt < 4; mt++)
                af[mt] = *(const bf16x8*)&As[(qr + mt * 16 + lr) * 128
                                            + (((ch * 4 + lg) ^ lr) * 8)];
#pragma unroll
            for (int nt = 0; nt < 4; nt++)
                bfr[nt] = *(const bf16x8*)&Bs[(qc + nt * 16 + lr) * 128
                                             + (((ch * 4 + lg) ^ lr) * 8)];
#pragma unroll
            for (int mt = 0; mt < 4; mt++)
#pragma unroll
                for (int nt = 0; nt < 4; nt++)
                    acc[mt][nt] = __builtin_amdgcn_mfma_f32_16x16x32_bf16(af[mt], bfr[nt], acc[mt][nt], 0, 0, 0);
        }
        __syncthreads();
    }

#pragma unroll
    for (int nt = 0; nt < 4; nt++) {
        int C = col0 + qc + nt * 16 + lr;
        float bias = bo[C];
#pragma unroll
        for (int mt = 0; mt < 4; mt++) {
#pragma unroll
            for (int r = 0; r < 4; r++) {
                int R = row0 + qr + mt * 16 + lg * 4 + r;
                out[(size_t)R * 768 + C] = acc[mt][nt][r] + bias;
            }
        }
    }
}

// ---------------------------------------------------------------------------
extern "C" void kernel_launch(void* const* d_in, const int* in_sizes, int n_in,
                              void* d_out, int out_size, void* d_ws, size_t ws_size,
                              hipStream_t stream)
{
    // All reference inputs are float32; output is float32.
    const float* inp0  = (const float*)d_in[0];
    const float* inp1  = (const float*)d_in[1];
    const float* amask = (const float*)d_in[2];
    const float* Wq0 = (const float*)d_in[3];
    const float* bq0 = (const float*)d_in[4];
    const float* Wk0 = (const float*)d_in[5];
    const float* bk0 = (const float*)d_in[6];
    const float* Wv0 = (const float*)d_in[7];
    const float* bv0 = (const float*)d_in[8];
    const float* Wq1 = (const float*)d_in[9];
    const float* bq1 = (const float*)d_in[10];
    const float* Wk1 = (const float*)d_in[11];
    const float* bk1 = (const float*)d_in[12];
    const float* Wv1 = (const float*)d_in[13];
    const float* bv1 = (const float*)d_in[14];
    const float* Wo  = (const float*)d_in[15];
    const float* bo  = (const float*)d_in[16];

    // Workspace layout (bytes), peak ~126.0 MB.
    // X aliases Ab0 (Ab0 is dead after qkv_all; stream order protects it).
    char* ws = (char*)d_ws;
    __bf16* WT0 = (__bf16*)(ws + 0);            // 1152x768  bf16 (1,769,472)
    __bf16* WT1 = (__bf16*)(ws + 1769472);      // 1152x1536 bf16 (3,538,944)
    __bf16* WoT = (__bf16*)(ws + 5308416);      // 768x768   bf16 (1,179,648)
    __bf16* Ab0 = (__bf16*)(ws + 6488064);      // 12.58M bf16 (25,165,824)
    __bf16* X   = Ab0;                          // alias
    __bf16* Ab1 = (__bf16*)(ws + 31653888);     // 12.58M bf16 (25,165,824)
    __bf16* Q0  = (__bf16*)(ws + 56819712);     // 8*6*2048*64 bf16 (12,582,912)
    __bf16* K0  = (__bf16*)(ws + 69402624);
    __bf16* V0T = (__bf16*)(ws + 81985536);
    __bf16* Q1  = (__bf16*)(ws + 94568448);     // 8*6*1024*64 bf16 (6,291,456)
    __bf16* K1  = (__bf16*)(ws + 100859904);
    __bf16* V1T = (__bf16*)(ws + 107151360);    // ends 113,442,816
    float* outp = (float*)d_out;

    hipLaunchKernelGGL(prep_all, dim3(13080), dim3(256), 0, stream,
                       inp0, inp1, Wq0, Wk0, Wv0, Wq1, Wk1, Wv1, Wo,
                       Ab0, Ab1, WT0, WT1, WoT);
    hipLaunchKernelGGL(qkv_all, dim3(1728), dim3(256), 0, stream,
                       Ab0, Ab1, WT0, WT1,
                       bq0, bk0, bv0, bq1, bk1, bv1, amask,
                       Q0, K0, V0T, Q1, K1, V1T);
    hipLaunchKernelGGL(attn_all, dim3(1344), dim3(512), 0, stream,
                       Q0, K0, V0T, Q1, K1, V1T, X, outp + 12582912);
    hipLaunchKernelGGL(out_gemm, dim3(768), dim3(256), 0, stream,
                       X, WoT, bo, outp);
}